// Round 9
// baseline (194.801 us; speedup 1.0000x reference)
//
#include <hip/hip_runtime.h>
#include <hip/hip_cooperative_groups.h>

namespace cg = cooperative_groups;

// ---------------------------------------------------------------------------
// LearnedBoardEncoder, factorized, single cooperative kernel (+ fallback).
//
// Token space is tiny: LN(W[c]@piece[p] + b[c] + square[s]) has 7*3*64=1344
// distinct rows; special tokens 2+16+9=27. Phase 1 (22 blocks): build the
// 1371-row LN'd table in workspace. grid.sync(). Phase 2: gather.
//
// R9: R8's coop gather was store-drain serialized (1.5 TB/s): vmcnt is an
// in-order FIFO, so each iteration's table-load wait drained the previous
// NT store to HBM. Fix = software pipeline (T14): idx loads 1 iter ahead;
// table loads for k+1 and idx loads for k+2 issued BEFORE stores of k.
// Grid sized by the driver's occupancy query (coop launch validates the
// same number). Checked launch + fallback to the proven R6 path.
// ---------------------------------------------------------------------------

#define DIM 256
#define NPT 7
#define NCOL 3
#define NROWS_SQ (NPT * NCOL * 64)   // 1344
#define ROW_TURN 1344                // 2 rows
#define ROW_CASTLE 1346              // 16 rows
#define ROW_EP 1362                  // 9 rows
#define NROWS_TOT 1371
#define EPSV 1e-5f
#define BATCH 4

typedef float f32x4 __attribute__((ext_vector_type(4)));

__device__ __forceinline__ float4 ln4(float4 x, float4 g, float4 bb) {
    float s = x.x + x.y + x.z + x.w;
    #pragma unroll
    for (int m = 1; m < 64; m <<= 1) s += __shfl_xor(s, m, 64);
    float mu = s * (1.0f / DIM);
    float dx = x.x - mu, dy = x.y - mu, dz = x.z - mu, dw = x.w - mu;
    float v = dx * dx + dy * dy + dz * dz + dw * dw;
    #pragma unroll
    for (int m = 1; m < 64; m <<= 1) v += __shfl_xor(v, m, 64);
    float inv = rsqrtf(v * (1.0f / DIM) + EPSV);
    return make_float4(dx * inv * g.x + bb.x,
                       dy * inv * g.y + bb.y,
                       dz * inv * g.z + bb.z,
                       dw * inv * g.w + bb.w);
}

__device__ __forceinline__ void build_table_block(
        int e, int tid, int wave, int lane,
        const float* __restrict__ piece_table,
        const float* __restrict__ W,
        const float* __restrict__ bvec,
        const float* __restrict__ square_table,
        const float* __restrict__ turn_table,
        const float* __restrict__ castling_table,
        const float* __restrict__ ep_table,
        const float* __restrict__ gamma,
        const float* __restrict__ beta,
        float* __restrict__ table) {
    if (e < NPT * NCOL) {
        int p = e / NCOL, c = e % NCOL;
        __shared__ float pt[DIM];
        __shared__ float projs[DIM];
        pt[tid] = piece_table[p * DIM + tid];
        __syncthreads();
        const float4* w4 = (const float4*)(W + (size_t)c * DIM * DIM + (size_t)tid * DIM);
        float acc = bvec[c * DIM + tid];
        #pragma unroll 8
        for (int k = 0; k < DIM / 4; ++k) {
            float4 w = w4[k];
            acc += w.x * pt[k * 4 + 0] + w.y * pt[k * 4 + 1]
                 + w.z * pt[k * 4 + 2] + w.w * pt[k * 4 + 3];
        }
        projs[tid] = acc;
        __syncthreads();

        float4 g  = ((const float4*)gamma)[lane];
        float4 bb = ((const float4*)beta)[lane];
        float4 a = ((const float4*)projs)[lane];
        float* tbase = table + (size_t)(p * (NCOL * 64) + c * 64) * DIM;
        for (int s = wave; s < 64; s += 4) {
            float4 q = ((const float4*)(square_table + s * DIM))[lane];
            float4 x = make_float4(a.x + q.x, a.y + q.y, a.z + q.z, a.w + q.w);
            ((float4*)(tbase + (size_t)s * DIM))[lane] = ln4(x, g, bb);
        }
    } else if (e == NPT * NCOL) {
        float4 g  = ((const float4*)gamma)[lane];
        float4 bb = ((const float4*)beta)[lane];
        for (int w = wave; w < 27; w += 4) {
            float4 x;
            if (w < 2) {
                x = ((const float4*)(turn_table + w * DIM))[lane];
            } else if (w < 18) {
                x = ((const float4*)(castling_table + (w - 2) * DIM))[lane];
            } else {
                x = ((const float4*)(ep_table + (w - 18) * DIM))[lane];
            }
            ((float4*)(table + (size_t)(ROW_TURN + w) * DIM))[lane] = ln4(x, g, bb);
        }
    }
}

// Issue the raw index loads for a batch WITHOUT consuming them (values are
// consumed later in resolve_row, so the loads stay in flight ~1 iteration).
__device__ __forceinline__ void load_idx_batch(
        int bbase, int nrows,
        const int* __restrict__ pi, const int* __restrict__ ci,
        const int* __restrict__ tu, const int* __restrict__ ca,
        const int* __restrict__ ep,
        int* __restrict__ A, int* __restrict__ Bv) {
    #pragma unroll
    for (int i = 0; i < BATCH; ++i) {
        int r = bbase + i; if (r >= nrows) r = nrows - 1;
        int b = r / 67;
        int t = r - b * 67;
        if (t >= 3) {
            int idx = b * 64 + (t - 3);
            A[i] = pi[idx]; Bv[i] = ci[idx];
        } else if (t == 0) { A[i] = tu[b]; Bv[i] = 0; }
        else if (t == 1)   { A[i] = ca[b]; Bv[i] = 0; }
        else               { A[i] = ep[b]; Bv[i] = 0; }
    }
}

__device__ __forceinline__ int resolve_row(int r, int nrows, int a, int bv) {
    if (r >= nrows) r = nrows - 1;
    int b = r / 67;
    int t = r - b * 67;
    if (t >= 3) return a * (NCOL * 64) + bv * 64 + (t - 3);
    if (t == 0) return ROW_TURN + a;
    if (t == 1) return ROW_CASTLE + a;
    return ROW_EP + a;
}

// ---- Fused cooperative kernel ----
__global__ __launch_bounds__(256) void fused_kernel(
        const int* __restrict__ piece_ids,
        const int* __restrict__ color_ids,
        const int* __restrict__ turn,
        const int* __restrict__ castling,
        const int* __restrict__ ep_file,
        const float* __restrict__ piece_table,
        const float* __restrict__ W,
        const float* __restrict__ bvec,
        const float* __restrict__ square_table,
        const float* __restrict__ turn_table,
        const float* __restrict__ castling_table,
        const float* __restrict__ ep_table,
        const float* __restrict__ gamma,
        const float* __restrict__ beta,
        float* __restrict__ table,
        float* __restrict__ out,
        int nrows) {
    int e = blockIdx.x;
    int tid = threadIdx.x;
    int wave = tid >> 6, lane = tid & 63;

    build_table_block(e, tid, wave, lane, piece_table, W, bvec, square_table,
                      turn_table, castling_table, ep_table, gamma, beta, table);

    cg::this_grid().sync();

    // -------- Phase 2: pipelined gather (idx 1 iter ahead; loads before
    // stores so no load-wait drains an outstanding NT store) --------
    int gw = e * 4 + wave;
    int nwaves = gridDim.x * 4;
    int step = nwaves * BATCH;
    int cur = gw * BATCH;
    if (cur >= nrows) return;

    int A[BATCH], Bv[BATCH];
    f32x4 v[BATCH];
    load_idx_batch(cur, nrows, piece_ids, color_ids, turn, castling, ep_file, A, Bv);
    #pragma unroll
    for (int i = 0; i < BATCH; ++i) {
        int row = resolve_row(cur + i, nrows, A[i], Bv[i]);
        v[i] = ((const f32x4*)table)[(size_t)row * (DIM / 4) + lane];
    }
    int nxt = cur + step;
    if (nxt < nrows)
        load_idx_batch(nxt, nrows, piece_ids, color_ids, turn, castling, ep_file, A, Bv);

    while (nxt < nrows) {
        // 1. table loads for batch nxt (consumes idx loads issued last iter)
        f32x4 vb[BATCH];
        #pragma unroll
        for (int i = 0; i < BATCH; ++i) {
            int row = resolve_row(nxt + i, nrows, A[i], Bv[i]);
            vb[i] = ((const f32x4*)table)[(size_t)row * (DIM / 4) + lane];
        }
        // 2. idx loads for batch nxt+step (in flight across the next iter)
        int n2 = nxt + step;
        if (n2 < nrows)
            load_idx_batch(n2, nrows, piece_ids, color_ids, turn, castling, ep_file, A, Bv);
        // 3. stores for batch cur (issued AFTER this iter's loads; their
        //    drain never blocks a later load-wait)
        #pragma unroll
        for (int i = 0; i < BATCH; ++i) {
            int r = cur + i;
            if (r < nrows)
                __builtin_nontemporal_store(v[i], (f32x4*)out + (size_t)r * (DIM / 4) + lane);
        }
        // 4. rotate
        #pragma unroll
        for (int i = 0; i < BATCH; ++i) v[i] = vb[i];
        cur = nxt; nxt = n2;
    }
    #pragma unroll
    for (int i = 0; i < BATCH; ++i) {
        int r = cur + i;
        if (r < nrows)
            __builtin_nontemporal_store(v[i], (f32x4*)out + (size_t)r * (DIM / 4) + lane);
    }
}

// ---- Fallback path: proven R6 kernels ----
__global__ __launch_bounds__(256) void table_kernel(
        const float* __restrict__ piece_table,
        const float* __restrict__ W,
        const float* __restrict__ bvec,
        const float* __restrict__ square_table,
        const float* __restrict__ turn_table,
        const float* __restrict__ castling_table,
        const float* __restrict__ ep_table,
        const float* __restrict__ gamma,
        const float* __restrict__ beta,
        float* __restrict__ table) {
    build_table_block(blockIdx.x, threadIdx.x, threadIdx.x >> 6, threadIdx.x & 63,
                      piece_table, W, bvec, square_table, turn_table,
                      castling_table, ep_table, gamma, beta, table);
}

__global__ void gather_kernel(const int* __restrict__ piece_ids,
                              const int* __restrict__ color_ids,
                              const int* __restrict__ turn,
                              const int* __restrict__ castling,
                              const int* __restrict__ ep_file,
                              const float* __restrict__ table,
                              float* __restrict__ out,
                              int nrows) {
    int r = blockIdx.x * 4 + (threadIdx.x >> 6);
    if (r >= nrows) return;
    int lane = threadIdx.x & 63;
    int b = r / 67;
    int t = r - b * 67;
    int row;
    if (t == 0)      row = ROW_TURN + turn[b];
    else if (t == 1) row = ROW_CASTLE + castling[b];
    else if (t == 2) row = ROW_EP + ep_file[b];
    else {
        int s = t - 3;
        int idx = b * 64 + s;
        row = piece_ids[idx] * (NCOL * 64) + color_ids[idx] * 64 + s;
    }
    f32x4 v = ((const f32x4*)(table + (size_t)row * DIM))[lane];
    __builtin_nontemporal_store(v, (f32x4*)(out + (size_t)r * DIM) + lane);
}

extern "C" void kernel_launch(void* const* d_in, const int* in_sizes, int n_in,
                              void* d_out, int out_size, void* d_ws, size_t ws_size,
                              hipStream_t stream) {
    const int*   piece_ids      = (const int*)d_in[0];
    const int*   color_ids      = (const int*)d_in[1];
    const int*   turn           = (const int*)d_in[2];
    const int*   castling       = (const int*)d_in[3];
    const int*   ep_file        = (const int*)d_in[4];
    const float* piece_table    = (const float*)d_in[5];
    const float* W              = (const float*)d_in[6];
    const float* bvec           = (const float*)d_in[7];
    const float* square_table   = (const float*)d_in[8];
    const float* turn_table     = (const float*)d_in[9];
    const float* castling_table = (const float*)d_in[10];
    const float* ep_table       = (const float*)d_in[11];
    const float* gamma          = (const float*)d_in[12];
    const float* beta           = (const float*)d_in[13];
    float* out = (float*)d_out;

    int B = in_sizes[0] / 64;
    int nrows = B * 67;
    float* table = (float*)d_ws;                 // 1371 * 256 floats

    // Grid: max co-resident blocks per the driver's own occupancy math
    // (the cooperative-launch check validates against the same number).
    int blocksPerCU = 0;
    hipError_t qe = hipOccupancyMaxActiveBlocksPerMultiprocessor(
        &blocksPerCU, fused_kernel, 256, 0);
    int grid = (qe == hipSuccess && blocksPerCU > 0) ? blocksPerCU * 256 : 512;
    if (grid > 2048) grid = 2048;
    if (grid < 512)  grid = 512;

    void* args[] = {
        (void*)&piece_ids, (void*)&color_ids, (void*)&turn, (void*)&castling,
        (void*)&ep_file, (void*)&piece_table, (void*)&W, (void*)&bvec,
        (void*)&square_table, (void*)&turn_table, (void*)&castling_table,
        (void*)&ep_table, (void*)&gamma, (void*)&beta,
        (void*)&table, (void*)&out, (void*)&nrows,
    };
    hipError_t err = hipLaunchCooperativeKernel((const void*)fused_kernel,
                                                dim3(grid), dim3(256),
                                                args, 0, stream);
    if (err != hipSuccess) {
        // Fallback: proven R6 three-kernel path.
        table_kernel<<<NPT * NCOL + 1, 256, 0, stream>>>(
            piece_table, W, bvec, square_table, turn_table, castling_table,
            ep_table, gamma, beta, table);
        gather_kernel<<<(nrows + 3) / 4, 256, 0, stream>>>(
            piece_ids, color_ids, turn, castling, ep_file, table, out, nrows);
    }
}

// Round 10
// 70.177 us; speedup vs baseline: 2.7759x; 2.7759x over previous
//
#include <hip/hip_runtime.h>

// ---------------------------------------------------------------------------
// LearnedBoardEncoder, factorized. TWO kernels (coop fusion abandoned:
// R8/R9 evidence — loop-carried gathers either drain NT stores via the
// in-order vmcnt FIFO or spill their pipeline arrays to scratch; the
// wave-per-row mass-dispatch gather hides store latency by wave churn).
//
// Token space: LN(W[c]@piece[p] + b[c] + square[s]) has 7*3*64=1344 distinct
// rows; special tokens 2+16+9=27. Kernel 1 (22 blocks) builds the 1371-row
// LN'd table. Kernel 2: one wave per output row, NT f32x4 stores
// (R6 controlled test: NT = −5.4 us; keeps table L2-resident).
//
// R10 = R6 (62.0 us best) with ONE change: proj+LN prologue merged into a
// single table_kernel (removes one launch gap + proj HBM round-trip).
// ---------------------------------------------------------------------------

#define DIM 256
#define NPT 7
#define NCOL 3
#define NROWS_SQ (NPT * NCOL * 64)   // 1344
#define ROW_TURN 1344                // 2 rows
#define ROW_CASTLE 1346              // 16 rows
#define ROW_EP 1362                  // 9 rows
#define NROWS_TOT 1371
#define EPSV 1e-5f

typedef float f32x4 __attribute__((ext_vector_type(4)));

__device__ __forceinline__ float4 ln4(float4 x, float4 g, float4 bb) {
    float s = x.x + x.y + x.z + x.w;
    #pragma unroll
    for (int m = 1; m < 64; m <<= 1) s += __shfl_xor(s, m, 64);
    float mu = s * (1.0f / DIM);
    float dx = x.x - mu, dy = x.y - mu, dz = x.z - mu, dw = x.w - mu;
    float v = dx * dx + dy * dy + dz * dz + dw * dw;
    #pragma unroll
    for (int m = 1; m < 64; m <<= 1) v += __shfl_xor(v, m, 64);
    float inv = rsqrtf(v * (1.0f / DIM) + EPSV);
    return make_float4(dx * inv * g.x + bb.x,
                       dy * inv * g.y + bb.y,
                       dz * inv * g.z + bb.z,
                       dw * inv * g.w + bb.w);
}

// ---- Kernel 1: build the whole 1371-row layernormed table in one launch.
// Blocks 0..20: (p,c) pair — matvec proj into LDS, then LN 64 square rows.
// Block 21: LN the 27 special rows.
__global__ __launch_bounds__(256) void table_kernel(
        const float* __restrict__ piece_table,
        const float* __restrict__ W,
        const float* __restrict__ bvec,
        const float* __restrict__ square_table,
        const float* __restrict__ turn_table,
        const float* __restrict__ castling_table,
        const float* __restrict__ ep_table,
        const float* __restrict__ gamma,
        const float* __restrict__ beta,
        float* __restrict__ table) {
    int e = blockIdx.x;
    int tid = threadIdx.x;
    int wave = tid >> 6, lane = tid & 63;
    float4 g  = ((const float4*)gamma)[lane];
    float4 bb = ((const float4*)beta)[lane];

    if (e < NPT * NCOL) {
        int p = e / NCOL, c = e % NCOL;
        __shared__ float pt[DIM];
        __shared__ float projs[DIM];
        pt[tid] = piece_table[p * DIM + tid];
        __syncthreads();
        const float4* w4 = (const float4*)(W + (size_t)c * DIM * DIM + (size_t)tid * DIM);
        float acc = bvec[c * DIM + tid];
        #pragma unroll 8
        for (int k = 0; k < DIM / 4; ++k) {
            float4 w = w4[k];
            acc += w.x * pt[k * 4 + 0] + w.y * pt[k * 4 + 1]
                 + w.z * pt[k * 4 + 2] + w.w * pt[k * 4 + 3];
        }
        projs[tid] = acc;
        __syncthreads();

        float4 a = ((const float4*)projs)[lane];
        float* tbase = table + (size_t)(p * (NCOL * 64) + c * 64) * DIM;
        for (int s = wave; s < 64; s += 4) {
            float4 q = ((const float4*)(square_table + s * DIM))[lane];
            float4 x = make_float4(a.x + q.x, a.y + q.y, a.z + q.z, a.w + q.w);
            ((float4*)(tbase + (size_t)s * DIM))[lane] = ln4(x, g, bb);
        }
    } else {
        for (int w = wave; w < 27; w += 4) {
            float4 x;
            if (w < 2) {
                x = ((const float4*)(turn_table + w * DIM))[lane];
            } else if (w < 18) {
                x = ((const float4*)(castling_table + (w - 2) * DIM))[lane];
            } else {
                x = ((const float4*)(ep_table + (w - 18) * DIM))[lane];
            }
            ((float4*)(table + (size_t)(ROW_TURN + w) * DIM))[lane] = ln4(x, g, bb);
        }
    }
}

// ---- Kernel 2: gather. One wave per output row; f32x4 row copy; NT stores.
// (Byte-identical logic to R6's gather — the proven 5.6 TB/s config.)
__global__ void gather_kernel(const int* __restrict__ piece_ids,
                              const int* __restrict__ color_ids,
                              const int* __restrict__ turn,
                              const int* __restrict__ castling,
                              const int* __restrict__ ep_file,
                              const float* __restrict__ table,
                              float* __restrict__ out,
                              int nrows) {
    int r = blockIdx.x * 4 + (threadIdx.x >> 6);
    if (r >= nrows) return;
    int lane = threadIdx.x & 63;
    int b = r / 67;
    int t = r - b * 67;
    int row;
    if (t == 0) {
        row = ROW_TURN + turn[b];
    } else if (t == 1) {
        row = ROW_CASTLE + castling[b];
    } else if (t == 2) {
        row = ROW_EP + ep_file[b];
    } else {
        int s = t - 3;
        int idx = b * 64 + s;
        row = piece_ids[idx] * (NCOL * 64) + color_ids[idx] * 64 + s;
    }
    f32x4 v = ((const f32x4*)(table + (size_t)row * DIM))[lane];
    __builtin_nontemporal_store(v, (f32x4*)(out + (size_t)r * DIM) + lane);
}

extern "C" void kernel_launch(void* const* d_in, const int* in_sizes, int n_in,
                              void* d_out, int out_size, void* d_ws, size_t ws_size,
                              hipStream_t stream) {
    const int*   piece_ids      = (const int*)d_in[0];
    const int*   color_ids      = (const int*)d_in[1];
    const int*   turn           = (const int*)d_in[2];
    const int*   castling       = (const int*)d_in[3];
    const int*   ep_file        = (const int*)d_in[4];
    const float* piece_table    = (const float*)d_in[5];
    const float* W              = (const float*)d_in[6];
    const float* bvec           = (const float*)d_in[7];
    const float* square_table   = (const float*)d_in[8];
    const float* turn_table     = (const float*)d_in[9];
    const float* castling_table = (const float*)d_in[10];
    const float* ep_table       = (const float*)d_in[11];
    const float* gamma          = (const float*)d_in[12];
    const float* beta           = (const float*)d_in[13];
    float* out = (float*)d_out;

    int B = in_sizes[0] / 64;
    int nrows = B * 67;
    float* table = (float*)d_ws;                 // 1371 * 256 floats

    table_kernel<<<NPT * NCOL + 1, 256, 0, stream>>>(
        piece_table, W, bvec, square_table, turn_table, castling_table,
        ep_table, gamma, beta, table);
    gather_kernel<<<(nrows + 3) / 4, 256, 0, stream>>>(
        piece_ids, color_ids, turn, castling, ep_file, table, out, nrows);
}